// Round 1
// baseline (667.881 us; speedup 1.0000x reference)
//
#include <hip/hip_runtime.h>
#include <math.h>

#define D 512
#define NC 64
#define NQ 2048

// ---- workspace float offsets ----
#define OFF_S    0
#define OFF_L    32
#define OFF_WT   (OFF_L + D*D)
#define OFF_AINV (OFF_WT + D*D)
#define OFF_MU   (OFF_AINV + D*D)
#define OFF_U    (OFF_MU + NC*D)
#define OFF_V    (OFF_U + NC*6*D)
#define OFF_P    (OFF_V + NC*6*D)
#define OFF_MINV (OFF_P + NC*D)
#define OFF_BIAS (OFF_MINV + NC*36)
#define OFF_H    (OFF_BIAS + NC)
#define OFF_SV   (OFF_H + NC)
#define OFF_G    (OFF_SV + NC*6)
#define OFF_AQ   (OFF_G + NQ*D)
#define OFF_B    (OFF_AQ + NQ)
#define OFF_T    (OFF_B + NQ*NC)
// total = OFF_T + NQ*NC*6 ~= 3.22M floats ~= 12.9 MB

__device__ inline float wred(float v) {
#pragma unroll
  for (int off = 32; off; off >>= 1) v += __shfl_down(v, off);
  return v;  // lane 0 holds sum
}

// scalars: kappa_n, sp, scale, bias_shared, weights, logdetA
__global__ void k_scalars(const float* __restrict__ kp, const float* __restrict__ nup,
                          const float* __restrict__ diag, float* __restrict__ S) {
  if (threadIdx.x != 0 || blockIdx.x != 0) return;
  float kappa = kp[0], nu = nup[0];
  float kn = fabsf(kappa) + 1e-6f + 5.0f;
  float sp = fmaxf(nu, (float)(D - 1) + 1e-6f) + 5.0f - (float)D + 2.0f;
  float bias_shared = lgammaf(0.5f * (sp + (float)D)) - lgammaf(0.5f * sp)
                    - 0.5f * (float)D * logf(sp);
  float w  = (fabsf(kappa) + 1e-6f) / kn;        // dm-outer weight
  float xw = 5.0f / kn;                          // xmean_weight
  float mw = fabsf(kappa + 1e-6f) / kn;          // m weight
  float scale = kn * sp / (kn + 1.0f);           // sigma multiplier
  float lda = 0.f;
  for (int i = 0; i < D; ++i) lda += logf(fabsf(diag[i]));
  lda *= 2.f;                                    // logdet A
  S[0] = kn; S[1] = sp; S[2] = scale; S[3] = bias_shared;
  S[4] = w;  S[5] = xw; S[6] = mw;   S[7] = lda;
  S[8] = 1.f / scale;
  S[9] = (float)D * logf(scale) + lda;           // logdet base (per-class adds logdet M)
  S[10] = 0.5f * (sp + (float)D);
  S[11] = 1.f / sp;
}

__global__ void k_build_L(const float* __restrict__ diag, const float* __restrict__ low,
                          float* __restrict__ L) {
  int t = blockIdx.x * 256 + threadIdx.x;
  if (t >= D * D) return;
  int i = t / D, j = t % D;
  float v;
  if (i == j)      v = fabsf(diag[i]);
  else if (i > j)  v = low[t];
  else             v = 0.f;
  L[t] = v;
}

// W = L^{-1}, stored transposed row-major: WT[j][i] = W[i][j]. One wave per column j.
__global__ void k_trinv(const float* __restrict__ L, float* __restrict__ WT) {
  __shared__ float x[D];
  int j = blockIdx.x;
  int lane = threadIdx.x;  // 64 threads = 1 wave
  for (int i = lane; i < D; i += 64) x[i] = 0.f;
  __syncthreads();
  for (int i = j; i < D; ++i) {
    float part = 0.f;
    for (int k = j + lane; k < i; k += 64) part += L[i * D + k] * x[k];
    part = wred(part);
    if (lane == 0) {
      float rhs = (i == j) ? 1.0f : 0.0f;
      x[i] = (rhs - part) / L[i * D + i];
    }
    __syncthreads();
  }
  for (int i = lane; i < D; i += 64) WT[j * D + i] = x[i];
}

// Generic "NT" matmul: C[m][n] = sum_k A[m*K+k] * B[n*K+k]; row-major, ldc=N.
// Requires M%64==0, N%64==0, K%16==0. 64x64 tile, 4x4 micro-tile, 256 threads.
__global__ __launch_bounds__(256) void k_nt(const float* __restrict__ A,
                                            const float* __restrict__ B,
                                            float* __restrict__ Cout,
                                            int M, int N, int K) {
  __shared__ float As[16][68];
  __shared__ float Bs[16][68];
  int bm = blockIdx.x * 64, bn = blockIdx.y * 64;
  int tid = threadIdx.x;
  int tx = tid & 15, ty = tid >> 4;
  int lrow = tid >> 2;          // 0..63
  int lk4  = (tid & 3) << 2;    // 0,4,8,12
  float acc[4][4] = {};
  for (int k0 = 0; k0 < K; k0 += 16) {
    float4 av = *reinterpret_cast<const float4*>(&A[(size_t)(bm + lrow) * K + k0 + lk4]);
    float4 bv = *reinterpret_cast<const float4*>(&B[(size_t)(bn + lrow) * K + k0 + lk4]);
    __syncthreads();
    As[lk4 + 0][lrow] = av.x; As[lk4 + 1][lrow] = av.y;
    As[lk4 + 2][lrow] = av.z; As[lk4 + 3][lrow] = av.w;
    Bs[lk4 + 0][lrow] = bv.x; Bs[lk4 + 1][lrow] = bv.y;
    Bs[lk4 + 2][lrow] = bv.z; Bs[lk4 + 3][lrow] = bv.w;
    __syncthreads();
#pragma unroll
    for (int kk = 0; kk < 16; ++kk) {
      float a0 = As[kk][ty * 4 + 0], a1 = As[kk][ty * 4 + 1];
      float a2 = As[kk][ty * 4 + 2], a3 = As[kk][ty * 4 + 3];
      float b0 = Bs[kk][tx * 4 + 0], b1 = Bs[kk][tx * 4 + 1];
      float b2 = Bs[kk][tx * 4 + 2], b3 = Bs[kk][tx * 4 + 3];
      acc[0][0] += a0 * b0; acc[0][1] += a0 * b1; acc[0][2] += a0 * b2; acc[0][3] += a0 * b3;
      acc[1][0] += a1 * b0; acc[1][1] += a1 * b1; acc[1][2] += a1 * b2; acc[1][3] += a1 * b3;
      acc[2][0] += a2 * b0; acc[2][1] += a2 * b1; acc[2][2] += a2 * b2; acc[2][3] += a2 * b3;
      acc[3][0] += a3 * b0; acc[3][1] += a3 * b1; acc[3][2] += a3 * b2; acc[3][3] += a3 * b3;
    }
  }
#pragma unroll
  for (int i = 0; i < 4; ++i)
#pragma unroll
    for (int j = 0; j < 4; ++j)
      Cout[(size_t)(bm + ty * 4 + i) * N + bn + tx * 4 + j] = acc[i][j];
}

// per class: x_mean, mu, U (D x 6: 5 shots /sqrt(5), sqrt(w)*dm)
__global__ void k_classprep(const float* __restrict__ Xs, const float* __restrict__ m,
                            const float* __restrict__ S,
                            float* __restrict__ MU, float* __restrict__ U) {
  int c = blockIdx.x;
  float xw = S[5], mw = S[6], sw = sqrtf(S[4]);
  const float is5 = 0.44721359549995793f;  // 1/sqrt(5)
  for (int d = threadIdx.x; d < D; d += blockDim.x) {
    float x0 = Xs[(size_t)(c * 5 + 0) * D + d];
    float x1 = Xs[(size_t)(c * 5 + 1) * D + d];
    float x2 = Xs[(size_t)(c * 5 + 2) * D + d];
    float x3 = Xs[(size_t)(c * 5 + 3) * D + d];
    float x4 = Xs[(size_t)(c * 5 + 4) * D + d];
    float xm = (x0 + x1 + x2 + x3 + x4) * 0.2f;
    float mv = m[d];
    MU[(size_t)c * D + d] = mw * mv + xw * xm;
    float dm = xm - mv;
    U[(size_t)(c * 6 + 0) * D + d] = x0 * is5;
    U[(size_t)(c * 6 + 1) * D + d] = x1 * is5;
    U[(size_t)(c * 6 + 2) * D + d] = x2 * is5;
    U[(size_t)(c * 6 + 3) * D + d] = x3 * is5;
    U[(size_t)(c * 6 + 4) * D + d] = x4 * is5;
    U[(size_t)(c * 6 + 5) * D + d] = sw * dm;
  }
}

// per class: M = I + U^T V (6x6), Cholesky -> Minv, logdetM, bias; s = V^T mu; h = mu^T Ainv mu
__global__ void k_msmall(const float* __restrict__ Ubuf, const float* __restrict__ Vbuf,
                         const float* __restrict__ MUbuf, const float* __restrict__ Pbuf,
                         const float* __restrict__ S,
                         float* __restrict__ Minv, float* __restrict__ biasv,
                         float* __restrict__ hbuf, float* __restrict__ svec) {
  int c = blockIdx.x, lane = threadIdx.x;
  __shared__ float Msh[36];
  for (int p = 0; p < 36; ++p) {
    int i = p / 6, j = p % 6;
    const float* u = Ubuf + (size_t)(c * 6 + i) * D;
    const float* v = Vbuf + (size_t)(c * 6 + j) * D;
    float part = 0.f;
    for (int d = lane; d < D; d += 64) part += u[d] * v[d];
    part = wred(part);
    if (lane == 0) Msh[p] = part + (i == j ? 1.f : 0.f);
  }
  for (int j = 0; j < 6; ++j) {
    const float* mu = MUbuf + (size_t)c * D;
    const float* v = Vbuf + (size_t)(c * 6 + j) * D;
    float part = 0.f;
    for (int d = lane; d < D; d += 64) part += mu[d] * v[d];
    part = wred(part);
    if (lane == 0) svec[c * 6 + j] = part;
  }
  {
    const float* mu = MUbuf + (size_t)c * D;
    const float* p = Pbuf + (size_t)c * D;
    float part = 0.f;
    for (int d = lane; d < D; d += 64) part += mu[d] * p[d];
    part = wred(part);
    if (lane == 0) hbuf[c] = part;
  }
  __syncthreads();
  if (lane == 0) {
    float Mm[6][6], R[6][6], Rin[6][6];
    for (int i = 0; i < 6; ++i)
      for (int j = 0; j < 6; ++j) { Mm[i][j] = Msh[i * 6 + j]; R[i][j] = 0.f; Rin[i][j] = 0.f; }
    float logdetM = 0.f;
    for (int i = 0; i < 6; ++i) {
      float s = Mm[i][i];
      for (int k = 0; k < i; ++k) s -= R[i][k] * R[i][k];
      float rii = sqrtf(s);
      R[i][i] = rii;
      logdetM += logf(rii);
      for (int r = i + 1; r < 6; ++r) {
        float s2 = Mm[r][i];
        for (int k = 0; k < i; ++k) s2 -= R[r][k] * R[i][k];
        R[r][i] = s2 / rii;
      }
    }
    logdetM *= 2.f;
    for (int j = 0; j < 6; ++j) {
      Rin[j][j] = 1.f / R[j][j];
      for (int i = j + 1; i < 6; ++i) {
        float s3 = 0.f;
        for (int k = j; k < i; ++k) s3 += R[i][k] * Rin[k][j];
        Rin[i][j] = -s3 / R[i][i];
      }
    }
    for (int i = 0; i < 6; ++i)
      for (int j = 0; j < 6; ++j) {
        float s4 = 0.f;
        for (int k = 0; k < 6; ++k) s4 += Rin[k][i] * Rin[k][j];
        Minv[c * 36 + i * 6 + j] = s4;
      }
    biasv[c] = S[3] - 0.5f * (S[9] + logdetM);
  }
}

__global__ void k_rowdot(const float* __restrict__ G, const float* __restrict__ Xq,
                         float* __restrict__ aq) {
  int q = blockIdx.x, lane = threadIdx.x;
  float p = 0.f;
  for (int d = lane; d < D; d += 64) p += G[(size_t)q * D + d] * Xq[(size_t)q * D + d];
  p = wred(p);
  if (lane == 0) aq[q] = p;
}

__global__ void k_final(const float* __restrict__ aq, const float* __restrict__ Bq,
                        const float* __restrict__ hbuf, const float* __restrict__ Tq,
                        const float* __restrict__ svec, const float* __restrict__ Minv,
                        const float* __restrict__ biasv, const float* __restrict__ S,
                        float* __restrict__ out) {
  int t = blockIdx.x * blockDim.x + threadIdx.x;
  if (t >= NQ * NC) return;
  int q = t >> 6, c = t & 63;
  float e[6];
#pragma unroll
  for (int j = 0; j < 6; ++j)
    e[j] = Tq[(size_t)q * (NC * 6) + c * 6 + j] - svec[c * 6 + j];
  float quad = 0.f;
#pragma unroll
  for (int i = 0; i < 6; ++i) {
    float acc = 0.f;
#pragma unroll
    for (int j = 0; j < 6; ++j) acc += Minv[c * 36 + i * 6 + j] * e[j];
    quad += e[i] * acc;
  }
  float dist = (aq[q] - 2.f * Bq[(size_t)q * NC + c] + hbuf[c] - quad) * S[8];
  out[t] = biasv[c] - S[10] * log1pf(dist * S[11]);
}

extern "C" void kernel_launch(void* const* d_in, const int* in_sizes, int n_in,
                              void* d_out, int out_size, void* d_ws, size_t ws_size,
                              hipStream_t stream) {
  const float* Xs   = (const float*)d_in[0];
  // d_in[1] = y (labels): contiguous SHOTS-per-class by construction; unused.
  const float* Xq   = (const float*)d_in[2];
  const float* m    = (const float*)d_in[3];
  const float* kap  = (const float*)d_in[4];
  const float* nu   = (const float*)d_in[5];
  const float* diag = (const float*)d_in[6];
  const float* low  = (const float*)d_in[7];
  float* ws = (float*)d_ws;

  float* S    = ws + OFF_S;
  float* L    = ws + OFF_L;
  float* WT   = ws + OFF_WT;
  float* Ainv = ws + OFF_AINV;
  float* MU   = ws + OFF_MU;
  float* U    = ws + OFF_U;
  float* V    = ws + OFF_V;
  float* P    = ws + OFF_P;
  float* Minv = ws + OFF_MINV;
  float* bias = ws + OFF_BIAS;
  float* hb   = ws + OFF_H;
  float* sv   = ws + OFF_SV;
  float* G    = ws + OFF_G;
  float* aq   = ws + OFF_AQ;
  float* Bq   = ws + OFF_B;
  float* Tq   = ws + OFF_T;

  hipLaunchKernelGGL(k_scalars, dim3(1), dim3(64), 0, stream, kap, nu, diag, S);
  hipLaunchKernelGGL(k_build_L, dim3(D * D / 256), dim3(256), 0, stream, diag, low, L);
  hipLaunchKernelGGL(k_trinv, dim3(D), dim3(64), 0, stream, L, WT);
  // Ainv = W^T W  (NT of WT with itself)
  hipLaunchKernelGGL(k_nt, dim3(D / 64, D / 64), dim3(256), 0, stream, WT, WT, Ainv, D, D, D);
  hipLaunchKernelGGL(k_classprep, dim3(NC), dim3(256), 0, stream, Xs, m, S, MU, U);
  // V = U @ Ainv   (rows: 384)
  hipLaunchKernelGGL(k_nt, dim3(NC * 6 / 64, D / 64), dim3(256), 0, stream, U, Ainv, V, NC * 6, D, D);
  // P = MU @ Ainv  (rows: 64)
  hipLaunchKernelGGL(k_nt, dim3(NC / 64, D / 64), dim3(256), 0, stream, MU, Ainv, P, NC, D, D);
  hipLaunchKernelGGL(k_msmall, dim3(NC), dim3(64), 0, stream, U, V, MU, P, S, Minv, bias, hb, sv);
  // G = Xq @ Ainv
  hipLaunchKernelGGL(k_nt, dim3(NQ / 64, D / 64), dim3(256), 0, stream, Xq, Ainv, G, NQ, D, D);
  // T = Xq @ V^T  (N=384)
  hipLaunchKernelGGL(k_nt, dim3(NQ / 64, NC * 6 / 64), dim3(256), 0, stream, Xq, V, Tq, NQ, NC * 6, D);
  // B = G @ MU^T  (N=64)
  hipLaunchKernelGGL(k_nt, dim3(NQ / 64, NC / 64), dim3(256), 0, stream, G, MU, Bq, NQ, NC, D);
  hipLaunchKernelGGL(k_rowdot, dim3(NQ), dim3(64), 0, stream, G, Xq, aq);
  hipLaunchKernelGGL(k_final, dim3(NQ * NC / 256), dim3(256), 0, stream,
                     aq, Bq, hb, Tq, sv, Minv, bias, S, (float*)d_out);
}

// Round 2
// 266.561 us; speedup vs baseline: 2.5055x; 2.5055x over previous
//
#include <hip/hip_runtime.h>
#include <math.h>

#define D 512
#define NC 64
#define NQ 2048
#define NR 448   // 384 U rows + 64 MU rows

// ---- workspace float offsets ----
#define OFF_S    0
#define OFF_L    32
#define OFF_W    (OFF_L + D*D)
#define OFF_TMP  (OFF_W + D*D)          // 256*256 max doubling temp
#define OFF_UB   (OFF_TMP + 65536)      // [U(384); MU(64)] : NR x D
#define OFF_UW   (OFF_UB + NR*D)        // [UW; MW] : NR x D
#define OFF_Y    (OFF_UW + NR*D)        // NQ x D
#define OFF_T2   (OFF_Y + NQ*D)         // NQ x NR
#define OFF_MINV (OFF_T2 + NQ*NR)       // NC*36
#define OFF_BIAS (OFF_MINV + NC*36)
#define OFF_H    (OFF_BIAS + NC)
#define OFF_AQ   (OFF_H + NC)
#define OFF_SV   (OFF_AQ + NQ)          // NC*6
// total ~ 3.02M floats ~ 12.1 MB

__device__ inline float wred(float v) {
#pragma unroll
  for (int off = 32; off; off >>= 1) v += __shfl_down(v, off);
  return v;  // lane 0 holds sum
}

__global__ void k_scalars(const float* __restrict__ kp, const float* __restrict__ nup,
                          const float* __restrict__ diag, float* __restrict__ S) {
  if (threadIdx.x != 0 || blockIdx.x != 0) return;
  float kappa = kp[0], nu = nup[0];
  float kn = fabsf(kappa) + 1e-6f + 5.0f;
  float sp = fmaxf(nu, (float)(D - 1) + 1e-6f) + 5.0f - (float)D + 2.0f;
  float bias_shared = lgammaf(0.5f * (sp + (float)D)) - lgammaf(0.5f * sp)
                    - 0.5f * (float)D * logf(sp);
  float w  = (fabsf(kappa) + 1e-6f) / kn;        // dm-outer weight
  float xw = 5.0f / kn;                          // xmean weight
  float mw = fabsf(kappa + 1e-6f) / kn;          // m weight
  float scale = kn * sp / (kn + 1.0f);           // sigma multiplier
  float lda = 0.f;
  for (int i = 0; i < D; ++i) lda += logf(fabsf(diag[i]));
  lda *= 2.f;                                    // logdet A
  S[0] = kn; S[1] = sp; S[2] = scale; S[3] = bias_shared;
  S[4] = w;  S[5] = xw; S[6] = mw;   S[7] = lda;
  S[8] = 1.f / scale;
  S[9] = (float)D * logf(scale) + lda;           // logdet base
  S[10] = 0.5f * (sp + (float)D);
  S[11] = 1.f / sp;
}

__global__ void k_build_L(const float* __restrict__ diag, const float* __restrict__ low,
                          float* __restrict__ L) {
  int t = blockIdx.x * 256 + threadIdx.x;
  if (t >= D * D) return;
  int i = t / D, j = t % D;
  float v;
  if (i == j)      v = fabsf(diag[i]);
  else if (i > j)  v = low[t];
  else             v = 0.f;
  L[t] = v;
}

// Invert the 8 diagonal 64x64 blocks of L into W. One wave per block,
// lane j owns column j, fully in LDS, lockstep over rows.
__global__ __launch_bounds__(64) void k_diaginv(const float* __restrict__ L,
                                                float* __restrict__ W) {
  __shared__ float Ls[64][65];
  __shared__ float xs[64][65];
  int p = blockIdx.x * 64;
  int lane = threadIdx.x;
  for (int idx = lane; idx < 64 * 64; idx += 64) {
    int r = idx >> 6, c = idx & 63;
    Ls[r][c] = L[(size_t)(p + r) * D + p + c];
    xs[r][c] = 0.f;
  }
  __syncthreads();
  int j = lane;
  for (int i = 0; i < 64; ++i) {
    float s = 0.f;
    for (int k = 0; k < i; ++k) s += Ls[i][k] * xs[k][j];
    float val = (((i == j) ? 1.0f : 0.0f) - s) / Ls[i][i];
    __syncthreads();
    xs[i][j] = val;
    __syncthreads();
  }
  for (int idx = lane; idx < 64 * 64; idx += 64) {
    int r = idx >> 6, c = idx & 63;
    W[(size_t)(p + r) * D + p + c] = xs[r][c];
  }
}

// Generic batched NN matmul on submatrices: C = alpha * A @ B, all n x n,
// with per-z linear offsets. 32x32 tile, 2x2 micro, 256 threads.
__global__ __launch_bounds__(256) void k_nn(const float* __restrict__ A, int lda, int aOff0, int aZ,
                                            const float* __restrict__ B, int ldb, int bOff0, int bZ,
                                            float* __restrict__ C, int ldc, int cOff0, int cZ,
                                            int n, float alpha) {
  __shared__ float As[32][33];
  __shared__ float Bs[32][33];
  const float* Ab = A + aOff0 + (size_t)blockIdx.z * aZ;
  const float* Bb = B + bOff0 + (size_t)blockIdx.z * bZ;
  float* Cb       = C + cOff0 + (size_t)blockIdx.z * cZ;
  int bm = blockIdx.y * 32, bn = blockIdx.x * 32;
  int tid = threadIdx.x;
  int tx = tid & 15, ty = tid >> 4;
  float acc[2][2] = {};
  for (int k0 = 0; k0 < n; k0 += 32) {
    __syncthreads();
    for (int idx = tid; idx < 1024; idx += 256) {
      int r = idx >> 5, c = idx & 31;
      As[r][c] = Ab[(size_t)(bm + r) * lda + k0 + c];
      Bs[r][c] = Bb[(size_t)(k0 + r) * ldb + bn + c];
    }
    __syncthreads();
#pragma unroll
    for (int kk = 0; kk < 32; ++kk) {
      float a0 = As[ty * 2 + 0][kk], a1 = As[ty * 2 + 1][kk];
      float b0 = Bs[kk][tx * 2 + 0], b1 = Bs[kk][tx * 2 + 1];
      acc[0][0] += a0 * b0; acc[0][1] += a0 * b1;
      acc[1][0] += a1 * b0; acc[1][1] += a1 * b1;
    }
  }
#pragma unroll
  for (int i = 0; i < 2; ++i)
#pragma unroll
    for (int j = 0; j < 2; ++j)
      Cb[(size_t)(bm + ty * 2 + i) * ldc + bn + tx * 2 + j] = alpha * acc[i][j];
}

// NT matmul: C[m][n] = sum_k A[m*K+k]*B[n*K+k]. M%64==0, N%64==0, K%16==0.
// btri: B rows are lower-triangular (row r nonzero only k<=r) -> clip K.
__global__ __launch_bounds__(256) void k_nt(const float* __restrict__ A,
                                            const float* __restrict__ B,
                                            float* __restrict__ Cout,
                                            int M, int N, int K, int btri) {
  __shared__ float As[16][68];
  __shared__ float Bs[16][68];
  int bm = blockIdx.x * 64, bn = blockIdx.y * 64;
  int Klim = btri ? min(K, bn + 64) : K;
  int tid = threadIdx.x;
  int tx = tid & 15, ty = tid >> 4;
  int lrow = tid >> 2;
  int lk4  = (tid & 3) << 2;
  float acc[4][4] = {};
  for (int k0 = 0; k0 < Klim; k0 += 16) {
    float4 av = *reinterpret_cast<const float4*>(&A[(size_t)(bm + lrow) * K + k0 + lk4]);
    float4 bv = *reinterpret_cast<const float4*>(&B[(size_t)(bn + lrow) * K + k0 + lk4]);
    __syncthreads();
    As[lk4 + 0][lrow] = av.x; As[lk4 + 1][lrow] = av.y;
    As[lk4 + 2][lrow] = av.z; As[lk4 + 3][lrow] = av.w;
    Bs[lk4 + 0][lrow] = bv.x; Bs[lk4 + 1][lrow] = bv.y;
    Bs[lk4 + 2][lrow] = bv.z; Bs[lk4 + 3][lrow] = bv.w;
    __syncthreads();
#pragma unroll
    for (int kk = 0; kk < 16; ++kk) {
      float a0 = As[kk][ty * 4 + 0], a1 = As[kk][ty * 4 + 1];
      float a2 = As[kk][ty * 4 + 2], a3 = As[kk][ty * 4 + 3];
      float b0 = Bs[kk][tx * 4 + 0], b1 = Bs[kk][tx * 4 + 1];
      float b2 = Bs[kk][tx * 4 + 2], b3 = Bs[kk][tx * 4 + 3];
      acc[0][0] += a0 * b0; acc[0][1] += a0 * b1; acc[0][2] += a0 * b2; acc[0][3] += a0 * b3;
      acc[1][0] += a1 * b0; acc[1][1] += a1 * b1; acc[1][2] += a1 * b2; acc[1][3] += a1 * b3;
      acc[2][0] += a2 * b0; acc[2][1] += a2 * b1; acc[2][2] += a2 * b2; acc[2][3] += a2 * b3;
      acc[3][0] += a3 * b0; acc[3][1] += a3 * b1; acc[3][2] += a3 * b2; acc[3][3] += a3 * b3;
    }
  }
#pragma unroll
  for (int i = 0; i < 4; ++i)
#pragma unroll
    for (int j = 0; j < 4; ++j)
      Cout[(size_t)(bm + ty * 4 + i) * N + bn + tx * 4 + j] = acc[i][j];
}

// per class: build Ubig = [5 shots /sqrt5 + sqrt(w)*dm (rows c*6..); MU (row 384+c)]
__global__ void k_classprep(const float* __restrict__ Xs, const float* __restrict__ m,
                            const float* __restrict__ S, float* __restrict__ Ub) {
  int c = blockIdx.x;
  float xw = S[5], mw = S[6], sw = sqrtf(S[4]);
  const float is5 = 0.44721359549995793f;  // 1/sqrt(5)
  for (int d = threadIdx.x; d < D; d += blockDim.x) {
    float x0 = Xs[(size_t)(c * 5 + 0) * D + d];
    float x1 = Xs[(size_t)(c * 5 + 1) * D + d];
    float x2 = Xs[(size_t)(c * 5 + 2) * D + d];
    float x3 = Xs[(size_t)(c * 5 + 3) * D + d];
    float x4 = Xs[(size_t)(c * 5 + 4) * D + d];
    float xm = (x0 + x1 + x2 + x3 + x4) * 0.2f;
    float mv = m[d];
    Ub[(size_t)(c * 6 + 0) * D + d] = x0 * is5;
    Ub[(size_t)(c * 6 + 1) * D + d] = x1 * is5;
    Ub[(size_t)(c * 6 + 2) * D + d] = x2 * is5;
    Ub[(size_t)(c * 6 + 3) * D + d] = x3 * is5;
    Ub[(size_t)(c * 6 + 4) * D + d] = x4 * is5;
    Ub[(size_t)(c * 6 + 5) * D + d] = sw * (xm - mv);
    Ub[(size_t)(384 + c) * D + d]   = mw * mv + xw * xm;
  }
}

// per class from UW=[UW;MW]: M = I + UW UW^T (6x6) -> Minv, logdetM, bias;
// sv = MW . UW_j ; h = ||MW||^2
__global__ __launch_bounds__(64) void k_msmall(const float* __restrict__ UW,
                                               const float* __restrict__ S,
                                               float* __restrict__ Minv, float* __restrict__ biasv,
                                               float* __restrict__ hbuf, float* __restrict__ svec) {
  int c = blockIdx.x, lane = threadIdx.x;
  __shared__ float Msh[36];
  const float* mw = UW + (size_t)(384 + c) * D;
  for (int p = 0; p < 36; ++p) {
    int i = p / 6, j = p % 6;
    const float* u = UW + (size_t)(c * 6 + i) * D;
    const float* v = UW + (size_t)(c * 6 + j) * D;
    float part = 0.f;
    for (int d = lane; d < D; d += 64) part += u[d] * v[d];
    part = wred(part);
    if (lane == 0) Msh[p] = part + (i == j ? 1.f : 0.f);
  }
  for (int j = 0; j < 6; ++j) {
    const float* v = UW + (size_t)(c * 6 + j) * D;
    float part = 0.f;
    for (int d = lane; d < D; d += 64) part += mw[d] * v[d];
    part = wred(part);
    if (lane == 0) svec[c * 6 + j] = part;
  }
  {
    float part = 0.f;
    for (int d = lane; d < D; d += 64) part += mw[d] * mw[d];
    part = wred(part);
    if (lane == 0) hbuf[c] = part;
  }
  __syncthreads();
  if (lane == 0) {
    float Mm[6][6], R[6][6], Rin[6][6];
    for (int i = 0; i < 6; ++i)
      for (int j = 0; j < 6; ++j) { Mm[i][j] = Msh[i * 6 + j]; R[i][j] = 0.f; Rin[i][j] = 0.f; }
    float logdetM = 0.f;
    for (int i = 0; i < 6; ++i) {
      float s = Mm[i][i];
      for (int k = 0; k < i; ++k) s -= R[i][k] * R[i][k];
      float rii = sqrtf(s);
      R[i][i] = rii;
      logdetM += logf(rii);
      for (int r = i + 1; r < 6; ++r) {
        float s2 = Mm[r][i];
        for (int k = 0; k < i; ++k) s2 -= R[r][k] * R[i][k];
        R[r][i] = s2 / rii;
      }
    }
    logdetM *= 2.f;
    for (int j = 0; j < 6; ++j) {
      Rin[j][j] = 1.f / R[j][j];
      for (int i = j + 1; i < 6; ++i) {
        float s3 = 0.f;
        for (int k = j; k < i; ++k) s3 += R[i][k] * Rin[k][j];
        Rin[i][j] = -s3 / R[i][i];
      }
    }
    for (int i = 0; i < 6; ++i)
      for (int j = 0; j < 6; ++j) {
        float s4 = 0.f;
        for (int k = 0; k < 6; ++k) s4 += Rin[k][i] * Rin[k][j];
        Minv[c * 36 + i * 6 + j] = s4;
      }
    biasv[c] = S[3] - 0.5f * (S[9] + logdetM);
  }
}

__global__ __launch_bounds__(64) void k_rowsumsq(const float* __restrict__ Y,
                                                 float* __restrict__ aq) {
  int q = blockIdx.x, lane = threadIdx.x;
  const float4* Y4 = reinterpret_cast<const float4*>(Y + (size_t)q * D);
  float p = 0.f;
  for (int idx = lane; idx < D / 4; idx += 64) {
    float4 v = Y4[idx];
    p += v.x * v.x + v.y * v.y + v.z * v.z + v.w * v.w;
  }
  p = wred(p);
  if (lane == 0) aq[q] = p;
}

__global__ void k_final(const float* __restrict__ aq, const float* __restrict__ T2,
                        const float* __restrict__ hbuf,
                        const float* __restrict__ svec, const float* __restrict__ Minv,
                        const float* __restrict__ biasv, const float* __restrict__ S,
                        float* __restrict__ out) {
  int t = blockIdx.x * blockDim.x + threadIdx.x;
  if (t >= NQ * NC) return;
  int q = t >> 6, c = t & 63;
  const float* t2 = T2 + (size_t)q * NR;
  float e[6];
#pragma unroll
  for (int j = 0; j < 6; ++j) e[j] = t2[c * 6 + j] - svec[c * 6 + j];
  float quad = 0.f;
#pragma unroll
  for (int i = 0; i < 6; ++i) {
    float acc = 0.f;
#pragma unroll
    for (int j = 0; j < 6; ++j) acc += Minv[c * 36 + i * 6 + j] * e[j];
    quad += e[i] * acc;
  }
  float xAmu = t2[384 + c];
  float dist = (aq[q] - 2.f * xAmu + hbuf[c] - quad) * S[8];
  out[t] = biasv[c] - S[10] * log1pf(dist * S[11]);
}

extern "C" void kernel_launch(void* const* d_in, const int* in_sizes, int n_in,
                              void* d_out, int out_size, void* d_ws, size_t ws_size,
                              hipStream_t stream) {
  const float* Xs   = (const float*)d_in[0];
  const float* Xq   = (const float*)d_in[2];
  const float* m    = (const float*)d_in[3];
  const float* kap  = (const float*)d_in[4];
  const float* nu   = (const float*)d_in[5];
  const float* diag = (const float*)d_in[6];
  const float* low  = (const float*)d_in[7];
  float* ws = (float*)d_ws;

  float* S    = ws + OFF_S;
  float* L    = ws + OFF_L;
  float* W    = ws + OFF_W;
  float* TMP  = ws + OFF_TMP;
  float* Ub   = ws + OFF_UB;
  float* UW   = ws + OFF_UW;
  float* Y    = ws + OFF_Y;
  float* T2   = ws + OFF_T2;
  float* Minv = ws + OFF_MINV;
  float* bias = ws + OFF_BIAS;
  float* hb   = ws + OFF_H;
  float* aq   = ws + OFF_AQ;
  float* sv   = ws + OFF_SV;

  hipLaunchKernelGGL(k_scalars, dim3(1), dim3(64), 0, stream, kap, nu, diag, S);
  hipLaunchKernelGGL(k_build_L, dim3(D * D / 256), dim3(256), 0, stream, diag, low, L);
  hipMemsetAsync(W, 0, (size_t)D * D * sizeof(float), stream);
  hipLaunchKernelGGL(k_diaginv, dim3(8), dim3(64), 0, stream, L, W);
  // recursive doubling: W[p+n.., p..] = -W_C @ (L_B @ W_A), levels n = 64,128,256
  for (int n = 64; n <= 256; n <<= 1) {
    int np = D / (2 * n);
    int g = n / 32;
    // TMP(z) = L[p+n.., p..] @ W[p.., p..]
    hipLaunchKernelGGL(k_nn, dim3(g, g, np), dim3(256), 0, stream,
                       L, D, n * D, 2 * n * (D + 1),
                       W, D, 0, 2 * n * (D + 1),
                       TMP, n, 0, n * n, n, 1.0f);
    // W[p+n.., p..] = -W[p+n.., p+n..] @ TMP(z)
    hipLaunchKernelGGL(k_nn, dim3(g, g, np), dim3(256), 0, stream,
                       W, D, n * (D + 1), 2 * n * (D + 1),
                       TMP, n, 0, n * n,
                       W, D, n * D, 2 * n * (D + 1), n, -1.0f);
  }
  hipLaunchKernelGGL(k_classprep, dim3(NC), dim3(256), 0, stream, Xs, m, S, Ub);
  // UW = [U; MU] @ W^T  (448 x 512 x 512, triangular-clipped)
  hipLaunchKernelGGL(k_nt, dim3(NR / 64, D / 64), dim3(256), 0, stream, Ub, W, UW, NR, D, D, 1);
  hipLaunchKernelGGL(k_msmall, dim3(NC), dim3(64), 0, stream, UW, S, Minv, bias, hb, sv);
  // Y = Xq @ W^T  (2048 x 512 x 512, triangular-clipped)
  hipLaunchKernelGGL(k_nt, dim3(NQ / 64, D / 64), dim3(256), 0, stream, Xq, W, Y, NQ, D, D, 1);
  // T2 = Y @ UW^T  (2048 x 448 x 512)
  hipLaunchKernelGGL(k_nt, dim3(NQ / 64, NR / 64), dim3(256), 0, stream, Y, UW, T2, NQ, NR, D, 0);
  hipLaunchKernelGGL(k_rowsumsq, dim3(NQ), dim3(64), 0, stream, Y, aq);
  hipLaunchKernelGGL(k_final, dim3(NQ * NC / 256), dim3(256), 0, stream,
                     aq, T2, hb, sv, Minv, bias, S, (float*)d_out);
}

// Round 3
// 181.030 us; speedup vs baseline: 3.6893x; 1.4725x over previous
//
#include <hip/hip_runtime.h>
#include <math.h>

#define D 512
#define NC 64
#define NQ 2048
#define NR 448   // 384 U rows + 64 MU rows
#define MT (NR + NQ)   // 2496 combined GEMM rows

// ---- workspace float offsets ----
#define OFF_S    0
#define OFF_L    32
#define OFF_W    (OFF_L + D*D)
#define OFF_TMP  (OFF_W + D*D)          // 256*256 max doubling temp
#define OFF_UB   (OFF_TMP + 65536)      // [U(384); MU(64)] : NR x D
#define OFF_YY   (OFF_UB + NR*D)        // [UW(384); MW(64); Y(2048)] : MT x D
#define OFF_T2   (OFF_YY + MT*D)        // NQ x NR
#define OFF_MINV (OFF_T2 + NQ*NR)       // NC*36
#define OFF_BIAS (OFF_MINV + NC*36)
#define OFF_H    (OFF_BIAS + NC)
#define OFF_AQ   (OFF_H + NC)
#define OFF_SV   (OFF_AQ + NQ)          // NC*6
// total ~ 3.02M floats ~ 12.1 MB

__device__ inline float wred(float v) {
#pragma unroll
  for (int off = 32; off; off >>= 1) v += __shfl_down(v, off);
  return v;  // lane 0 holds sum
}

__global__ __launch_bounds__(64) void k_scalars(const float* __restrict__ kp,
                                                const float* __restrict__ nup,
                                                const float* __restrict__ diag,
                                                float* __restrict__ S) {
  int lane = threadIdx.x;
  float part = 0.f;
  for (int i = lane; i < D; i += 64) part += logf(fabsf(diag[i]));
  part = wred(part);
  if (lane != 0) return;
  float lda = 2.f * part;                        // logdet A
  float kappa = kp[0], nu = nup[0];
  float kn = fabsf(kappa) + 1e-6f + 5.0f;
  float sp = fmaxf(nu, (float)(D - 1) + 1e-6f) + 5.0f - (float)D + 2.0f;
  float bias_shared = lgammaf(0.5f * (sp + (float)D)) - lgammaf(0.5f * sp)
                    - 0.5f * (float)D * logf(sp);
  float w  = (fabsf(kappa) + 1e-6f) / kn;
  float xw = 5.0f / kn;
  float mw = fabsf(kappa + 1e-6f) / kn;
  float scale = kn * sp / (kn + 1.0f);
  S[0] = kn; S[1] = sp; S[2] = scale; S[3] = bias_shared;
  S[4] = w;  S[5] = xw; S[6] = mw;   S[7] = lda;
  S[8] = 1.f / scale;
  S[9] = (float)D * logf(scale) + lda;
  S[10] = 0.5f * (sp + (float)D);
  S[11] = 1.f / sp;
}

// build L; also zero W's strict upper triangle (needed by k_nn reads)
__global__ void k_build_L(const float* __restrict__ diag, const float* __restrict__ low,
                          float* __restrict__ L, float* __restrict__ W) {
  int t = blockIdx.x * 256 + threadIdx.x;
  if (t >= D * D) return;
  int i = t / D, j = t % D;
  float v;
  if (i == j)      v = fabsf(diag[i]);
  else if (i > j)  v = low[t];
  else             v = 0.f;
  L[t] = v;
  if (i < j) W[t] = 0.f;
}

// Invert the 8 diagonal 64x64 blocks of L into W. One wave per block.
__global__ __launch_bounds__(64) void k_diaginv(const float* __restrict__ L,
                                                float* __restrict__ W) {
  __shared__ float Ls[64][65];
  __shared__ float xs[64][65];
  int p = blockIdx.x * 64;
  int lane = threadIdx.x;
  for (int idx = lane; idx < 64 * 64; idx += 64) {
    int r = idx >> 6, c = idx & 63;
    Ls[r][c] = L[(size_t)(p + r) * D + p + c];
    xs[r][c] = 0.f;
  }
  __syncthreads();
  int j = lane;
  for (int i = 0; i < 64; ++i) {
    float s = 0.f;
    for (int k = 0; k < i; ++k) s += Ls[i][k] * xs[k][j];
    float val = (((i == j) ? 1.0f : 0.0f) - s) / Ls[i][i];
    __syncthreads();
    xs[i][j] = val;
    __syncthreads();
  }
  for (int idx = lane; idx < 64 * 64; idx += 64) {
    int r = idx >> 6, c = idx & 63;
    W[(size_t)(p + r) * D + p + c] = xs[r][c];
  }
}

// Batched NN matmul on submatrices: C = alpha * A @ B, all n x n.
__global__ __launch_bounds__(256) void k_nn(const float* __restrict__ A, int lda, int aOff0, int aZ,
                                            const float* __restrict__ B, int ldb, int bOff0, int bZ,
                                            float* __restrict__ C, int ldc, int cOff0, int cZ,
                                            int n, float alpha) {
  __shared__ float As[32][33];
  __shared__ float Bs[32][33];
  const float* Ab = A + aOff0 + (size_t)blockIdx.z * aZ;
  const float* Bb = B + bOff0 + (size_t)blockIdx.z * bZ;
  float* Cb       = C + cOff0 + (size_t)blockIdx.z * cZ;
  int bm = blockIdx.y * 32, bn = blockIdx.x * 32;
  int tid = threadIdx.x;
  int tx = tid & 15, ty = tid >> 4;
  float acc[2][2] = {};
  for (int k0 = 0; k0 < n; k0 += 32) {
    __syncthreads();
    for (int idx = tid; idx < 1024; idx += 256) {
      int r = idx >> 5, c = idx & 31;
      As[r][c] = Ab[(size_t)(bm + r) * lda + k0 + c];
      Bs[r][c] = Bb[(size_t)(k0 + r) * ldb + bn + c];
    }
    __syncthreads();
#pragma unroll
    for (int kk = 0; kk < 32; ++kk) {
      float a0 = As[ty * 2 + 0][kk], a1 = As[ty * 2 + 1][kk];
      float b0 = Bs[kk][tx * 2 + 0], b1 = Bs[kk][tx * 2 + 1];
      acc[0][0] += a0 * b0; acc[0][1] += a0 * b1;
      acc[1][0] += a1 * b0; acc[1][1] += a1 * b1;
    }
  }
#pragma unroll
  for (int i = 0; i < 2; ++i)
#pragma unroll
    for (int j = 0; j < 2; ++j)
      Cb[(size_t)(bm + ty * 2 + i) * ldc + bn + tx * 2 + j] = alpha * acc[i][j];
}

// NT matmul with gathered A: row r reads A0 (r<split) else A1 (r-split).
// C[m][n] = sum_k Arow_m[k] * B[n*K+k]. M%64==0, N%64==0, K%16==0.
// btri: B rows lower-triangular -> clip K at bn+64.
// aq (optional): for blockIdx.y==0, also write row sum-of-squares of A rows.
__global__ __launch_bounds__(256) void k_ntg(const float* __restrict__ A0,
                                             const float* __restrict__ A1, int split,
                                             const float* __restrict__ B,
                                             float* __restrict__ Cout,
                                             int M, int N, int K, int btri,
                                             float* __restrict__ aq) {
  __shared__ float As[16][68];
  __shared__ float Bs[16][68];
  int bm = blockIdx.x * 64, bn = blockIdx.y * 64;
  int Klim = btri ? min(K, bn + 64) : K;
  int tid = threadIdx.x;
  int tx = tid & 15, ty = tid >> 4;
  int lrow = tid >> 2;
  int lk4  = (tid & 3) << 2;
  int r = bm + lrow;
  const float* arow = (r < split) ? (A0 + (size_t)r * K) : (A1 + (size_t)(r - split) * K);
  const float* brow = B + (size_t)(bn + lrow) * K;
  float acc[4][4] = {};
  float sq = 0.f;
  bool do_aq = (aq != nullptr) && (blockIdx.y == 0);
  for (int k0 = 0; k0 < Klim; k0 += 16) {
    float4 av = *reinterpret_cast<const float4*>(&arow[k0 + lk4]);
    float4 bv = *reinterpret_cast<const float4*>(&brow[k0 + lk4]);
    if (do_aq) sq += av.x * av.x + av.y * av.y + av.z * av.z + av.w * av.w;
    __syncthreads();
    As[lk4 + 0][lrow] = av.x; As[lk4 + 1][lrow] = av.y;
    As[lk4 + 2][lrow] = av.z; As[lk4 + 3][lrow] = av.w;
    Bs[lk4 + 0][lrow] = bv.x; Bs[lk4 + 1][lrow] = bv.y;
    Bs[lk4 + 2][lrow] = bv.z; Bs[lk4 + 3][lrow] = bv.w;
    __syncthreads();
#pragma unroll
    for (int kk = 0; kk < 16; ++kk) {
      float a0 = As[kk][ty * 4 + 0], a1 = As[kk][ty * 4 + 1];
      float a2 = As[kk][ty * 4 + 2], a3 = As[kk][ty * 4 + 3];
      float b0 = Bs[kk][tx * 4 + 0], b1 = Bs[kk][tx * 4 + 1];
      float b2 = Bs[kk][tx * 4 + 2], b3 = Bs[kk][tx * 4 + 3];
      acc[0][0] += a0 * b0; acc[0][1] += a0 * b1; acc[0][2] += a0 * b2; acc[0][3] += a0 * b3;
      acc[1][0] += a1 * b0; acc[1][1] += a1 * b1; acc[1][2] += a1 * b2; acc[1][3] += a1 * b3;
      acc[2][0] += a2 * b0; acc[2][1] += a2 * b1; acc[2][2] += a2 * b2; acc[2][3] += a2 * b3;
      acc[3][0] += a3 * b0; acc[3][1] += a3 * b1; acc[3][2] += a3 * b2; acc[3][3] += a3 * b3;
    }
  }
  if (do_aq) {
    sq += __shfl_down(sq, 2);
    sq += __shfl_down(sq, 1);
    if ((tid & 3) == 0) aq[r] = sq;
  }
#pragma unroll
  for (int i = 0; i < 4; ++i)
#pragma unroll
    for (int j = 0; j < 4; ++j)
      Cout[(size_t)(bm + ty * 4 + i) * N + bn + tx * 4 + j] = acc[i][j];
}

// per class: build Ub = [5 shots /sqrt5; sqrt(w)*dm] rows c*6.., MU row 384+c
__global__ void k_classprep(const float* __restrict__ Xs, const float* __restrict__ m,
                            const float* __restrict__ S, float* __restrict__ Ub) {
  int c = blockIdx.x;
  float xw = S[5], mw = S[6], sw = sqrtf(S[4]);
  const float is5 = 0.44721359549995793f;  // 1/sqrt(5)
  for (int d = threadIdx.x; d < D; d += blockDim.x) {
    float x0 = Xs[(size_t)(c * 5 + 0) * D + d];
    float x1 = Xs[(size_t)(c * 5 + 1) * D + d];
    float x2 = Xs[(size_t)(c * 5 + 2) * D + d];
    float x3 = Xs[(size_t)(c * 5 + 3) * D + d];
    float x4 = Xs[(size_t)(c * 5 + 4) * D + d];
    float xm = (x0 + x1 + x2 + x3 + x4) * 0.2f;
    float mv = m[d];
    Ub[(size_t)(c * 6 + 0) * D + d] = x0 * is5;
    Ub[(size_t)(c * 6 + 1) * D + d] = x1 * is5;
    Ub[(size_t)(c * 6 + 2) * D + d] = x2 * is5;
    Ub[(size_t)(c * 6 + 3) * D + d] = x3 * is5;
    Ub[(size_t)(c * 6 + 4) * D + d] = x4 * is5;
    Ub[(size_t)(c * 6 + 5) * D + d] = sw * (xm - mv);
    Ub[(size_t)(384 + c) * D + d]   = mw * mv + xw * xm;
  }
}

// per class: stage 7 rows (6 UW + MW) in LDS, 7x7 Gram via 4 waves,
// then 6x6 Cholesky -> Minv, logdetM, bias; sv, h.
__global__ __launch_bounds__(256) void k_msmall(const float* __restrict__ YY,
                                                const float* __restrict__ S,
                                                float* __restrict__ Minv, float* __restrict__ biasv,
                                                float* __restrict__ hbuf, float* __restrict__ svec) {
  __shared__ float4 R4[7 * 128];
  __shared__ float Dsh[49];
  int c = blockIdx.x, tid = threadIdx.x;
  int lane = tid & 63, wave = tid >> 6;
  for (int idx = tid; idx < 7 * 128; idx += 256) {
    int row = idx >> 7, c4 = idx & 127;
    const float* src = (row < 6) ? (YY + (size_t)(c * 6 + row) * D)
                                 : (YY + (size_t)(384 + c) * D);
    R4[row * 128 + c4] = reinterpret_cast<const float4*>(src)[c4];
  }
  __syncthreads();
  const float* R = reinterpret_cast<const float*>(R4);
  const int PI[28] = {0,0,0,0,0,0,0, 1,1,1,1,1,1, 2,2,2,2,2, 3,3,3,3, 4,4,4, 5,5, 6};
  const int PJ[28] = {0,1,2,3,4,5,6, 1,2,3,4,5,6, 2,3,4,5,6, 3,4,5,6, 4,5,6, 5,6, 6};
  for (int p = wave; p < 28; p += 4) {
    int i = PI[p], j = PJ[p];
    float part = 0.f;
#pragma unroll
    for (int it = 0; it < 8; ++it) {
      int d = lane + it * 64;
      part += R[i * D + d] * R[j * D + d];
    }
    part = wred(part);
    if (lane == 0) { Dsh[i * 7 + j] = part; Dsh[j * 7 + i] = part; }
  }
  __syncthreads();
  if (tid == 0) {
    float Mm[6][6], Rc[6][6], Rin[6][6];
    for (int i = 0; i < 6; ++i)
      for (int j = 0; j < 6; ++j) {
        Mm[i][j] = Dsh[i * 7 + j] + (i == j ? 1.f : 0.f);
        Rc[i][j] = 0.f; Rin[i][j] = 0.f;
      }
    float logdetM = 0.f;
    for (int i = 0; i < 6; ++i) {
      float s = Mm[i][i];
      for (int k = 0; k < i; ++k) s -= Rc[i][k] * Rc[i][k];
      float rii = sqrtf(s);
      Rc[i][i] = rii;
      logdetM += logf(rii);
      for (int r = i + 1; r < 6; ++r) {
        float s2 = Mm[r][i];
        for (int k = 0; k < i; ++k) s2 -= Rc[r][k] * Rc[i][k];
        Rc[r][i] = s2 / rii;
      }
    }
    logdetM *= 2.f;
    for (int j = 0; j < 6; ++j) {
      Rin[j][j] = 1.f / Rc[j][j];
      for (int i = j + 1; i < 6; ++i) {
        float s3 = 0.f;
        for (int k = j; k < i; ++k) s3 += Rc[i][k] * Rin[k][j];
        Rin[i][j] = -s3 / Rc[i][i];
      }
    }
    for (int i = 0; i < 6; ++i)
      for (int j = 0; j < 6; ++j) {
        float s4 = 0.f;
        for (int k = 0; k < 6; ++k) s4 += Rin[k][i] * Rin[k][j];
        Minv[c * 36 + i * 6 + j] = s4;
      }
    for (int j = 0; j < 6; ++j) svec[c * 6 + j] = Dsh[j * 7 + 6];
    hbuf[c] = Dsh[48];
    biasv[c] = S[3] - 0.5f * (S[9] + logdetM);
  }
}

__global__ void k_final(const float* __restrict__ aq, const float* __restrict__ T2,
                        const float* __restrict__ hbuf,
                        const float* __restrict__ svec, const float* __restrict__ Minv,
                        const float* __restrict__ biasv, const float* __restrict__ S,
                        float* __restrict__ out) {
  int t = blockIdx.x * blockDim.x + threadIdx.x;
  if (t >= NQ * NC) return;
  int q = t >> 6, c = t & 63;
  const float* t2 = T2 + (size_t)q * NR;
  float e[6];
#pragma unroll
  for (int j = 0; j < 6; ++j) e[j] = t2[c * 6 + j] - svec[c * 6 + j];
  float quad = 0.f;
#pragma unroll
  for (int i = 0; i < 6; ++i) {
    float acc = 0.f;
#pragma unroll
    for (int j = 0; j < 6; ++j) acc += Minv[c * 36 + i * 6 + j] * e[j];
    quad += e[i] * acc;
  }
  float xAmu = t2[384 + c];
  float dist = (aq[q] - 2.f * xAmu + hbuf[c] - quad) * S[8];
  out[t] = biasv[c] - S[10] * log1pf(dist * S[11]);
}

extern "C" void kernel_launch(void* const* d_in, const int* in_sizes, int n_in,
                              void* d_out, int out_size, void* d_ws, size_t ws_size,
                              hipStream_t stream) {
  const float* Xs   = (const float*)d_in[0];
  const float* Xq   = (const float*)d_in[2];
  const float* m    = (const float*)d_in[3];
  const float* kap  = (const float*)d_in[4];
  const float* nu   = (const float*)d_in[5];
  const float* diag = (const float*)d_in[6];
  const float* low  = (const float*)d_in[7];
  float* ws = (float*)d_ws;

  float* S    = ws + OFF_S;
  float* L    = ws + OFF_L;
  float* W    = ws + OFF_W;
  float* TMP  = ws + OFF_TMP;
  float* Ub   = ws + OFF_UB;
  float* YY   = ws + OFF_YY;   // rows 0..447 = UW/MW, rows 448.. = Y
  float* T2   = ws + OFF_T2;
  float* Minv = ws + OFF_MINV;
  float* bias = ws + OFF_BIAS;
  float* hb   = ws + OFF_H;
  float* aq   = ws + OFF_AQ;
  float* sv   = ws + OFF_SV;

  hipLaunchKernelGGL(k_scalars, dim3(1), dim3(64), 0, stream, kap, nu, diag, S);
  hipLaunchKernelGGL(k_build_L, dim3(D * D / 256), dim3(256), 0, stream, diag, low, L, W);
  hipLaunchKernelGGL(k_classprep, dim3(NC), dim3(256), 0, stream, Xs, m, S, Ub);
  hipLaunchKernelGGL(k_diaginv, dim3(8), dim3(64), 0, stream, L, W);
  // recursive doubling: W[p+n.., p..] = -W_C @ (L_B @ W_A), levels n = 64,128,256
  for (int n = 64; n <= 256; n <<= 1) {
    int np = D / (2 * n);
    int g = n / 32;
    hipLaunchKernelGGL(k_nn, dim3(g, g, np), dim3(256), 0, stream,
                       L, D, n * D, 2 * n * (D + 1),
                       W, D, 0, 2 * n * (D + 1),
                       TMP, n, 0, n * n, n, 1.0f);
    hipLaunchKernelGGL(k_nn, dim3(g, g, np), dim3(256), 0, stream,
                       W, D, n * (D + 1), 2 * n * (D + 1),
                       TMP, n, 0, n * n,
                       W, D, n * D, 2 * n * (D + 1), n, -1.0f);
  }
  // YY = [Ub; Xq] @ W^T  (2496 x 512 x 512, triangular-clipped)
  hipLaunchKernelGGL(k_ntg, dim3(MT / 64, D / 64), dim3(256), 0, stream,
                     Ub, Xq, NR, W, YY, MT, D, D, 1, (float*)nullptr);
  hipLaunchKernelGGL(k_msmall, dim3(NC), dim3(256), 0, stream, YY, S, Minv, bias, hb, sv);
  // T2 = Y @ [UW;MW]^T  (2048 x 448 x 512), fused aq = rowsumsq(Y)
  hipLaunchKernelGGL(k_ntg, dim3(NQ / 64, NR / 64), dim3(256), 0, stream,
                     YY + (size_t)NR * D, YY + (size_t)NR * D, 0, YY, T2, NQ, NR, D, 0, aq);
  hipLaunchKernelGGL(k_final, dim3(NQ * NC / 256), dim3(256), 0, stream,
                     aq, T2, hb, sv, Minv, bias, S, (float*)d_out);
}